// Round 14
// baseline (687.892 us; speedup 1.0000x reference)
//
#include <hip/hip_runtime.h>
#include <hip/hip_bf16.h>

typedef __bf16 bf16x4 __attribute__((ext_vector_type(4)));
typedef float f32x4 __attribute__((ext_vector_type(4)));
typedef float f32x2 __attribute__((ext_vector_type(2)));
typedef unsigned char u8;
typedef unsigned long long u64;

#define EPS 1e-5f

static __device__ __forceinline__ int lower_bound_i(const int* __restrict__ arr, int n, int val) {
  int lo = 0, hi = n;
  while (lo < hi) { int mid = (lo + hi) >> 1; if (arr[mid] < val) lo = mid + 1; else hi = mid; }
  return lo;
}

// ---- 16-lane sum via DPP (pure VALU) ----
template <int CTRL>
static __device__ __forceinline__ float dpp_add(float x) {
  int s = __builtin_amdgcn_mov_dpp(__float_as_int(x), CTRL, 0xF, 0xF, true);
  return x + __int_as_float(s);
}
static __device__ __forceinline__ float row16_reduce(float t) {
  t = dpp_add<0xB1>(t);   // xor1
  t = dpp_add<0x4E>(t);   // xor2
  t = dpp_add<0x141>(t);  // xor4 (row_half_mirror)
  t = dpp_add<0x140>(t);  // xor8 (row_mirror)
  return t;
}

// ---- fp8 e4m3 (OCP) helpers ----
static __device__ __forceinline__ u8 f32_to_fp8(float v) {
  int pk = __builtin_amdgcn_cvt_pk_fp8_f32(v, v, 0, false);
  return (u8)(pk & 0xFF);
}
static __device__ __forceinline__ unsigned pack4_fp8(float a, float b, float c, float d) {
  int w = __builtin_amdgcn_cvt_pk_fp8_f32(a, b, 0, false);
  w = __builtin_amdgcn_cvt_pk_fp8_f32(c, d, w, true);
  return (unsigned)w;
}

// ---------------- dtype detection ----------------
__global__ void detect_dtypes(const unsigned* __restrict__ xw, const unsigned* __restrict__ eiw,
                              int* __restrict__ flags) {
  __shared__ int s_bf16, s_i64nz;
  int t = threadIdx.x;
  if (t == 0) { s_bf16 = 0; s_i64nz = 0; }
  __syncthreads();
  unsigned w = xw[t * 97];
  unsigned lo = w & 0xFFFFu;
  unsigned e = (lo >> 7) & 0xFF;
  int looks_bf16 = (lo == 0u) || (e >= 0x6A && e <= 0x86);
  atomicAdd(&s_bf16, looks_bf16);
  int k = t * 1031;
  int nz = (eiw[2 * k + 1] != 0u) ? 1 : 0;
  atomicAdd(&s_i64nz, nz);
  __syncthreads();
  if (t == 0) {
    flags[0] = (s_bf16 >= 192) ? 1 : 0;
    flags[1] = (s_i64nz == 0) ? 1 : 0;
  }
}

// ---------------- merged float-side canonicalization ----------------
struct ParamDesc { const void* src[12]; int off[13]; };

// range 0: x (vec4 groups) -> h_f32 + h8 ; range 1: params -> f32 ; range 2: Wl|Wr -> fp8
__global__ void canon_all(const void* __restrict__ xsrc, ParamDesc pd,
                          const void* __restrict__ w1, const void* __restrict__ w2,
                          float* __restrict__ h_f32, u8* __restrict__ h8,
                          float* __restrict__ params, u8* __restrict__ w8,
                          int n_x4, int n_par, int n_w, const int* __restrict__ flags) {
  int i = blockIdx.x * blockDim.x + threadIdx.x;
  int isbf = flags[0];
  if (i < n_x4) {
    float v0, v1, v2, v3;
    if (isbf) {
      bf16x4 u = ((const bf16x4*)xsrc)[i];
      v0 = (float)u[0]; v1 = (float)u[1]; v2 = (float)u[2]; v3 = (float)u[3];
    } else {
      float4 u = ((const float4*)xsrc)[i];
      v0 = u.x; v1 = u.y; v2 = u.z; v3 = u.w;
    }
    ((float4*)h_f32)[i] = make_float4(v0, v1, v2, v3);
    ((unsigned*)h8)[i] = pack4_fp8(v0, v1, v2, v3);
    return;
  }
  i -= n_x4;
  if (i < n_par) {
    int s = 0;
#pragma unroll
    for (int k = 1; k < 12; k++) if (i >= pd.off[k]) s = k;
    int j = i - pd.off[s];
    const void* sp = pd.src[s];
    params[i] = isbf ? (float)((const __bf16*)sp)[j] : ((const float*)sp)[j];
    return;
  }
  i -= n_par;
  if (i < 2 * n_w) {
    const void* sp = (i < n_w) ? w1 : w2;
    int j = (i < n_w) ? i : i - n_w;
    float v = isbf ? (float)((const __bf16*)sp)[j] : ((const float*)sp)[j];
    w8[i] = f32_to_fp8(v);
  }
}

// merged: edge_index + batch int canonicalization + degree count (incl self-loops)
__global__ void canon_ints(const void* __restrict__ ei_src, const void* __restrict__ bat_src,
                           int* __restrict__ ei32, int* __restrict__ bat32,
                           int* __restrict__ deg, int E, int N, const int* __restrict__ flags) {
  int i = blockIdx.x * blockDim.x + threadIdx.x;
  int total = 2 * E + N;
  if (i >= total) return;
  int i64 = flags[1];
  if (i < 2 * E) {
    int v = i64 ? (int)((const long long*)ei_src)[i] : ((const int*)ei_src)[i];
    ei32[i] = v;
    if (i >= E) atomicAdd(&deg[v], 1);
  } else {
    int j = i - 2 * E;
    int v = i64 ? (int)((const long long*)bat_src)[j] : ((const int*)bat_src)[j];
    bat32[j] = v;
    atomicAdd(&deg[j], 1);   // self-loop
  }
}

// ---------------- CSR scan (+ degree histogram for load-balance perm) ----------------
__global__ __launch_bounds__(256) void block_sums(const int* __restrict__ deg,
                                                  int* __restrict__ bsum,
                                                  int* __restrict__ hist, int N) {
  __shared__ int sh[256];
  __shared__ int lh[64];
  int i = blockIdx.x * 256 + threadIdx.x;
  int t = threadIdx.x;
  int v = (i < N) ? deg[i] : 0;
  sh[t] = v;
  if (t < 64) lh[t] = 0;
  __syncthreads();
  if (i < N) atomicAdd(&lh[min(v, 63)], 1);
  for (int off = 128; off > 0; off >>= 1) {
    if (t < off) sh[t] += sh[t + off];
    __syncthreads();
  }
  if (t == 0) bsum[blockIdx.x] = sh[0];
  if (t < 64 && lh[t]) atomicAdd(&hist[t], lh[t]);
}

__global__ __launch_bounds__(256) void scan_bsums(const int* __restrict__ bsum,
                                                  int* __restrict__ bpref, int nblocks,
                                                  int* __restrict__ offs, int N,
                                                  const int* __restrict__ hist,
                                                  int* __restrict__ bcur) {
  __shared__ int sh[256];
  int t = threadIdx.x;
  int carry = 0;
  for (int base = 0; base < nblocks; base += 256) {
    int idx = base + t;
    int v = (idx < nblocks) ? bsum[idx] : 0;
    sh[t] = v;
    __syncthreads();
    for (int off = 1; off < 256; off <<= 1) {
      int u = (t >= off) ? sh[t - off] : 0;
      __syncthreads();
      sh[t] += u;
      __syncthreads();
    }
    if (idx < nblocks) bpref[idx] = carry + sh[t] - v;
    carry += sh[255];
    __syncthreads();
  }
  if (t == 0) offs[N] = carry;
  // 64-bin exclusive scan of degree histogram -> bucket cursors
  __syncthreads();
  if (t < 64) sh[t] = hist[t];
  __syncthreads();
  for (int off = 1; off < 64; off <<= 1) {
    int u = (t >= off && t < 64) ? sh[t - off] : 0;
    __syncthreads();
    if (t < 64) sh[t] += u;
    __syncthreads();
  }
  if (t < 64) bcur[t] = (t == 0) ? 0 : sh[t - 1];
}

__global__ __launch_bounds__(256) void write_offs(const int* __restrict__ deg,
                                                  const int* __restrict__ bpref,
                                                  int* __restrict__ offs,
                                                  int* __restrict__ cursor,
                                                  int* __restrict__ bcur,
                                                  int* __restrict__ perm, int N) {
  __shared__ int sh[256];
  int i = blockIdx.x * 256 + threadIdx.x;
  int t = threadIdx.x;
  int v = (i < N) ? deg[i] : 0;
  sh[t] = v;
  __syncthreads();
  for (int off = 1; off < 256; off <<= 1) {
    int u = (t >= off) ? sh[t - off] : 0;
    __syncthreads();
    sh[t] += u;
    __syncthreads();
  }
  if (i < N) {
    int ex = bpref[blockIdx.x] + sh[t] - v;
    offs[i] = ex;
    cursor[i] = ex;
    // degree-sorted permutation for gat load balance
    int pos = atomicAdd(&bcur[min(v, 63)], 1);
    perm[pos] = i;
  }
}

// csr_src stores BYTE offsets (src*1024)
__global__ void fill_csr(const int* __restrict__ ei, int E, int N,
                         int* __restrict__ cursor, int* __restrict__ csr_src) {
  int e = blockIdx.x * blockDim.x + threadIdx.x;
  if (e >= E + N) return;
  int s, d;
  if (e < E) { s = ei[e]; d = ei[E + e]; } else { s = e - E; d = e - E; }
  int pos = atomicAdd(&cursor[d], 1);
  csr_src[pos] = s * 1024;
}

// ---------------- GEMM (fp8 in, fp8 out), swapped operands => packed stores ----------------
__global__ __launch_bounds__(256) void gemm_xlr(
    const u8* __restrict__ A8, const u8* __restrict__ Wl8,
    const u8* __restrict__ Wr8, const float* __restrict__ bl,
    const float* __restrict__ br, u8* __restrict__ out8, int Nrows) {
  __shared__ u64 As[128][19];
  __shared__ u64 Ws[128][19];
  const int jb = blockIdx.y;
  const u8* Wbase = (jb < 4) ? (Wl8 + (size_t)jb * 16384) : (Wr8 + (size_t)(jb - 4) * 16384);
  const float* biasbase = (jb < 4) ? (bl + jb * 128) : (br + (jb - 4) * 128);
  const int row0 = blockIdx.x * 128;
  const int tid = threadIdx.x;
  const int lane = tid & 63, wave = tid >> 6;
  const int wm = wave >> 1, wn = wave & 1;

#pragma unroll
  for (int p = 0; p < 4; p++) {
    int r = (tid >> 3) + p * 32;
    int qc = (tid & 7) * 2;
    int gr = row0 + r;
    uint4 av = make_uint4(0, 0, 0, 0);
    if (gr < Nrows) av = *(const uint4*)(A8 + (size_t)gr * 128 + qc * 8);
    As[r][qc]     = ((u64)av.y << 32) | av.x;
    As[r][qc + 1] = ((u64)av.w << 32) | av.z;
    uint4 wv = *(const uint4*)(Wbase + (size_t)r * 128 + qc * 8);
    Ws[r][qc]     = ((u64)wv.y << 32) | wv.x;
    Ws[r][qc + 1] = ((u64)wv.w << 32) | wv.z;
  }
  __syncthreads();

  f32x4 acc[4][4];
#pragma unroll
  for (int mi = 0; mi < 4; mi++)
#pragma unroll
    for (int ni = 0; ni < 4; ni++) acc[mi][ni] = f32x4{0.f, 0.f, 0.f, 0.f};

#pragma unroll
  for (int ks = 0; ks < 4; ks++) {
    int qk = ks * 4 + (lane >> 4);
    long af[4], bf[4];
#pragma unroll
    for (int i = 0; i < 4; i++) {
      af[i] = (long)As[wm * 64 + i * 16 + (lane & 15)][qk];
      bf[i] = (long)Ws[wn * 64 + i * 16 + (lane & 15)][qk];
    }
#pragma unroll
    for (int mi = 0; mi < 4; mi++)
#pragma unroll
      for (int ni = 0; ni < 4; ni++)
        acc[mi][ni] = __builtin_amdgcn_mfma_f32_16x16x32_fp8_fp8(bf[ni], af[mi], acc[mi][ni], 0, 0, 0);
  }

#pragma unroll
  for (int mi = 0; mi < 4; mi++) {
    int gr = row0 + wm * 64 + mi * 16 + (lane & 15);
    if (gr >= Nrows) continue;
#pragma unroll
    for (int ni = 0; ni < 4; ni++) {
      int col_base = wn * 64 + ni * 16 + (lane >> 4) * 4;   // 4 consecutive cols
      float4 b4 = *(const float4*)(biasbase + col_base);
      unsigned pk = pack4_fp8(acc[mi][ni][0] + b4.x, acc[mi][ni][1] + b4.y,
                              acc[mi][ni][2] + b4.z, acc[mi][ni][3] + b4.w);
      *(unsigned*)(out8 + (size_t)gr * 1024 + jb * 128 + col_base) = pk;
    }
  }
}

// ---------------- fused GAT layer (fp8 gather, 2-edge form, degree-sorted perm) ----------------
__global__ __launch_bounds__(256) void gat_fused(
    const u8* __restrict__ comb8, const float* __restrict__ att,
    const int* __restrict__ offs, const int* __restrict__ csr_src,
    const int* __restrict__ perm,
    const float* __restrict__ conv_bias, const float* __restrict__ gamma,
    const float* __restrict__ beta, float* __restrict__ h_f32,
    u8* __restrict__ h8, int N, int store_fp8) {
  int wid = blockIdx.x * 4 + (threadIdx.x >> 6);
  int lane = threadIdx.x & 63;
  if (wid >= N) return;
  int n = perm[wid];   // degree-sorted: co-scheduled waves have similar edge counts
  f32x2 xr2[4], at2[4];
  uint2 wr = *(const uint2*)(comb8 + (size_t)n * 1024 + 512 + lane * 8);
  xr2[0] = __builtin_amdgcn_cvt_pk_f32_fp8(wr.x, false);
  xr2[1] = __builtin_amdgcn_cvt_pk_f32_fp8(wr.x, true);
  xr2[2] = __builtin_amdgcn_cvt_pk_f32_fp8(wr.y, false);
  xr2[3] = __builtin_amdgcn_cvt_pk_f32_fp8(wr.y, true);
  float4 a0 = *(const float4*)(att + lane * 8);
  float4 a1 = *(const float4*)(att + lane * 8 + 4);
  at2[0] = f32x2{a0.x, a0.y}; at2[1] = f32x2{a0.z, a0.w};
  at2[2] = f32x2{a1.x, a1.y}; at2[3] = f32x2{a1.z, a1.w};

  int off0 = offs[n], off1 = offs[n + 1];
  float l = 0.f;
  f32x2 acc2[4];
#pragma unroll
  for (int j = 0; j < 4; j++) acc2[j] = f32x2{0.f, 0.f};

  const u8* lane_base = comb8 + lane * 8;

  auto process = [&](uint2 w) {
    f32x2 x2[4];
    x2[0] = __builtin_amdgcn_cvt_pk_f32_fp8(w.x, false);
    x2[1] = __builtin_amdgcn_cvt_pk_f32_fp8(w.x, true);
    x2[2] = __builtin_amdgcn_cvt_pk_f32_fp8(w.y, false);
    x2[3] = __builtin_amdgcn_cvt_pk_f32_fp8(w.y, true);
    f32x2 t2 = f32x2{0.f, 0.f};
#pragma unroll
    for (int j = 0; j < 4; j++) {
      f32x2 z = x2[j] + xr2[j];
      f32x2 lz = __builtin_elementwise_max(z, 0.2f * z);   // leaky_relu, packed
      t2 = t2 + lz * at2[j];
    }
    float t = t2[0] + t2[1];
    t = row16_reduce(t);                 // 4 DPP VALU ops
    t = fminf(fmaxf(t, -60.f), 60.f);    // guard; softmax shift-invariant
    float p = __expf(t);
    l += p;
    f32x2 p2 = f32x2{p, p};
#pragma unroll
    for (int j = 0; j < 4; j++) acc2[j] = acc2[j] + p2 * x2[j];
  };

  int pos = off0;
  for (; pos + 2 <= off1; pos += 2) {
    int b0 = csr_src[pos], b1 = csr_src[pos + 1];  // premultiplied byte offsets
    uint2 wa = *(const uint2*)(lane_base + (size_t)(unsigned)b0);
    uint2 wb = *(const uint2*)(lane_base + (size_t)(unsigned)b1);
    process(wa);
    process(wb);
  }
  if (pos < off1) {
    int b0 = csr_src[pos];
    uint2 wa = *(const uint2*)(lane_base + (size_t)(unsigned)b0);
    process(wa);
  }

  float invl = 1.0f / fmaxf(l, 1e-30f);
  float acc[8];
#pragma unroll
  for (int j = 0; j < 4; j++) {
    acc[2 * j]     = acc2[j][0] * invl;
    acc[2 * j + 1] = acc2[j][1] * invl;
  }
#pragma unroll
  for (int j = 0; j < 8; j++) {
    acc[j] += __shfl_xor(acc[j], 16);
    acc[j] += __shfl_xor(acc[j], 32);
  }
  int c0 = (lane & 15) * 8;
  float v[8];
  float s = 0.f, s2 = 0.f;
#pragma unroll
  for (int j = 0; j < 8; j++) {
    v[j] = acc[j] * 0.25f + conv_bias[c0 + j];
    s += v[j]; s2 += v[j] * v[j];
  }
  s = row16_reduce(s);
  s2 = row16_reduce(s2);
  float mu = s * (1.f / 128.f);
  float var = fmaxf(s2 * (1.f / 128.f) - mu * mu, 0.f);
  float rs = rsqrtf(var + EPS);
  if (lane < 16) {
    float4 o0, o1;
    float hn[8];
#pragma unroll
    for (int j = 0; j < 8; j++) {
      float o = (v[j] - mu) * rs * gamma[c0 + j] + beta[c0 + j];
      o = o > 0.f ? o : 0.f;
      hn[j] = h_f32[(size_t)n * 128 + c0 + j] + o;
    }
    o0.x = hn[0]; o0.y = hn[1]; o0.z = hn[2]; o0.w = hn[3];
    o1.x = hn[4]; o1.y = hn[5]; o1.z = hn[6]; o1.w = hn[7];
    *(float4*)(h_f32 + (size_t)n * 128 + c0) = o0;
    *(float4*)(h_f32 + (size_t)n * 128 + c0 + 4) = o1;
    if (store_fp8) {
      uint2 pk;
      pk.x = pack4_fp8(hn[0], hn[1], hn[2], hn[3]);
      pk.y = pack4_fp8(hn[4], hn[5], hn[6], hn[7]);
      *(uint2*)(h8 + (size_t)n * 128 + c0) = pk;
    }
  }
}

// ---------------- global mean pool (separate, wide launch) ----------------
__global__ __launch_bounds__(128) void pool(const float* __restrict__ h_f32,
                                            const int* __restrict__ batch, int N,
                                            float* __restrict__ g_sum) {
  int g = blockIdx.x >> 4, slice = blockIdx.x & 15;
  int c = threadIdx.x;
  int r0 = lower_bound_i(batch, N, g);
  int r1 = lower_bound_i(batch, N, g + 1);
  int len = r1 - r0;
  if (len <= 0) return;
  int per = (len + 15) / 16;
  int s0 = r0 + slice * per;
  int s1 = min(s0 + per, r1);
  if (s0 >= s1) return;
  float acc = 0.f;
  for (int r = s0; r < s1; r++) acc += h_f32[(size_t)r * 128 + c];
  atomicAdd(&g_sum[g * 128 + c], acc);
}

// ---------------- MLP head + output layernorm ----------------
__global__ __launch_bounds__(256) void mlp_head(
    const float* __restrict__ g_sum, const int* __restrict__ batch, int N,
    const float* __restrict__ W1, const float* __restrict__ b1,
    const float* __restrict__ W2, const float* __restrict__ b2,
    const float* __restrict__ og, const float* __restrict__ ob,
    void* __restrict__ outv, const int* __restrict__ flags) {
  __shared__ float gld[128];
  __shared__ float hid[256];
  __shared__ float olds[128];
  __shared__ float red[2];
  int b = blockIdx.x, t = threadIdx.x;
  int r0 = lower_bound_i(batch, N, b);
  int r1 = lower_bound_i(batch, N, b + 1);
  int len = r1 - r0;
  float cntf = (float)(len < 1 ? 1 : len);
  if (t < 128) gld[t] = g_sum[b * 128 + t] / cntf;
  __syncthreads();
  float sacc = b1[t];
  for (int d = 0; d < 128; d++) sacc = fmaf(gld[d], W1[(size_t)t * 128 + d], sacc);
  hid[t] = 0.5f * sacc * (1.f + erff(sacc * 0.70710678118654752f));
  __syncthreads();
  if (t < 128) {
    float o = b2[t];
    for (int k = 0; k < 256; k++) o = fmaf(hid[k], W2[(size_t)t * 256 + k], o);
    olds[t] = o;
  }
  __syncthreads();
  if (t < 64) {
    float a = olds[t], bb = olds[t + 64];
    float s = a + bb, s2 = a * a + bb * bb;
    for (int off = 32; off; off >>= 1) { s += __shfl_down(s, off); s2 += __shfl_down(s2, off); }
    if (t == 0) { red[0] = s * (1.f / 128.f); red[1] = s2 * (1.f / 128.f); }
  }
  __syncthreads();
  if (t < 128) {
    float mu = red[0];
    float var = fmaxf(red[1] - mu * mu, 0.f);
    float rs = rsqrtf(var + EPS);
    float o = (olds[t] - mu) * rs * og[t] + ob[t];
    if (flags[0]) ((__bf16*)outv)[b * 128 + t] = (__bf16)o;
    else          ((float*)outv)[b * 128 + t] = o;
  }
}

extern "C" void kernel_launch(void* const* d_in, const int* in_sizes, int n_in,
                              void* d_out, int out_size, void* d_ws, size_t ws_size,
                              hipStream_t stream) {
  const int D = 128, B = 64;
  const int N = in_sizes[0] / D;
  const int E = in_sizes[1] / 2;
  const int EN = E + N;
  const int nsb = (N + 255) / 256;

  char* p = (char*)d_ws;
  auto alloc = [&](size_t bytes) {
    char* r = p; p += (bytes + 255) & ~(size_t)255; return (void*)r;
  };
  int* flags     = (int*)alloc(256);
  float* h_f32   = (float*)alloc((size_t)N * 128 * 4);
  u8* h8         = (u8*)alloc((size_t)N * 128);
  u8* comb8      = (u8*)alloc((size_t)N * 1024);
  int* deg       = (int*)alloc((size_t)N * 4);      // deg, hist, bcur contiguous
  int* hist      = (int*)alloc(256);
  int* bcur      = (int*)alloc(256);
  int* offs      = (int*)alloc((size_t)(N + 1) * 4);
  int* cursor    = (int*)alloc((size_t)N * 4);
  int* perm      = (int*)alloc((size_t)N * 4);
  int* csr_src   = (int*)alloc((size_t)EN * 4);
  float* g_sum   = (float*)alloc((size_t)B * 128 * 4);
  int* ei32      = (int*)alloc((size_t)2 * E * 4);
  int* bat32     = (int*)alloc((size_t)N * 4);
  int* bsum      = (int*)alloc((size_t)nsb * 4);
  int* bpref     = (int*)alloc((size_t)nsb * 4);
  u8* w8         = (u8*)alloc((size_t)2 * 196608);
  float* params  = (float*)alloc((size_t)71936 * 4);

  float* bl_c  = params + 0;
  float* br_c  = params + 1536;
  float* att_c = params + 3072;
  float* cb_c  = params + 4608;
  float* g_c   = params + 4992;
  float* b_c   = params + 5376;
  float* W1_c  = params + 5760;
  float* b1_c  = params + 38528;
  float* W2_c  = params + 38784;
  float* b2_c  = params + 71552;
  float* og_c  = params + 71680;
  float* ob_c  = params + 71808;

  detect_dtypes<<<1, 256, 0, stream>>>((const unsigned*)d_in[0], (const unsigned*)d_in[1], flags);

  ParamDesc pd;
  const int srcidx[12] = {4, 6, 7, 8, 9, 10, 11, 12, 13, 14, 15, 16};
  const int sizes12[12] = {1536, 1536, 1536, 384, 384, 384, 32768, 256, 32768, 128, 128, 128};
  int cum = 0;
  for (int k = 0; k < 12; k++) { pd.src[k] = d_in[srcidx[k]]; pd.off[k] = cum; cum += sizes12[k]; }
  pd.off[12] = cum;

  const int n_x4 = N * 32;
  const int n_w = 196608;
  const int canon_total = n_x4 + cum + 2 * n_w;
  canon_all<<<(canon_total + 255) / 256, 256, 0, stream>>>(
      d_in[0], pd, d_in[3], d_in[5], h_f32, h8, params, w8, n_x4, cum, n_w, flags);

  // zero deg + hist + bcur in one shot (contiguous allocs)
  size_t degR = ((size_t)N * 4 + 255) & ~(size_t)255;
  hipMemsetAsync(deg, 0, degR + 512, stream);
  hipMemsetAsync(g_sum, 0, (size_t)B * 128 * 4, stream);

  canon_ints<<<(2 * E + N + 255) / 256, 256, 0, stream>>>(d_in[1], d_in[2], ei32, bat32, deg, E, N, flags);
  block_sums<<<nsb, 256, 0, stream>>>(deg, bsum, hist, N);
  scan_bsums<<<1, 256, 0, stream>>>(bsum, bpref, nsb, offs, N, hist, bcur);
  write_offs<<<nsb, 256, 0, stream>>>(deg, bpref, offs, cursor, bcur, perm, N);
  fill_csr<<<(EN + 255) / 256, 256, 0, stream>>>(ei32, E, N, cursor, csr_src);

  for (int l = 0; l < 3; l++) {
    gemm_xlr<<<dim3((N + 127) / 128, 8), 256, 0, stream>>>(
        h8, w8 + (size_t)l * 65536, w8 + 196608 + (size_t)l * 65536,
        bl_c + l * 512, br_c + l * 512, comb8, N);
    gat_fused<<<(N + 3) / 4, 256, 0, stream>>>(comb8, att_c + l * 512, offs, csr_src, perm,
        cb_c + l * 128, g_c + l * 128, b_c + l * 128, h_f32, h8, N, (l < 2) ? 1 : 0);
  }
  pool<<<B * 16, 128, 0, stream>>>(h_f32, bat32, N, g_sum);
  mlp_head<<<B, 256, 0, stream>>>(g_sum, bat32, N, W1_c, b1_c, W2_c, b2_c, og_c, ob_c, d_out, flags);
}

// Round 15
// 517.536 us; speedup vs baseline: 1.3292x; 1.3292x over previous
//
#include <hip/hip_runtime.h>
#include <hip/hip_bf16.h>

typedef __bf16 bf16x4 __attribute__((ext_vector_type(4)));
typedef float f32x4 __attribute__((ext_vector_type(4)));
typedef float f32x2 __attribute__((ext_vector_type(2)));
typedef unsigned char u8;
typedef unsigned long long u64;

#define EPS 1e-5f

static __device__ __forceinline__ int lower_bound_i(const int* __restrict__ arr, int n, int val) {
  int lo = 0, hi = n;
  while (lo < hi) { int mid = (lo + hi) >> 1; if (arr[mid] < val) lo = mid + 1; else hi = mid; }
  return lo;
}

// ---- 16-lane sum via DPP (pure VALU) ----
template <int CTRL>
static __device__ __forceinline__ float dpp_add(float x) {
  int s = __builtin_amdgcn_mov_dpp(__float_as_int(x), CTRL, 0xF, 0xF, true);
  return x + __int_as_float(s);
}
static __device__ __forceinline__ float row16_reduce(float t) {
  t = dpp_add<0xB1>(t);   // xor1
  t = dpp_add<0x4E>(t);   // xor2
  t = dpp_add<0x141>(t);  // xor4 (row_half_mirror)
  t = dpp_add<0x140>(t);  // xor8 (row_mirror)
  return t;
}

// ---- fp8 e4m3 (OCP) helpers ----
static __device__ __forceinline__ u8 f32_to_fp8(float v) {
  int pk = __builtin_amdgcn_cvt_pk_fp8_f32(v, v, 0, false);
  return (u8)(pk & 0xFF);
}
static __device__ __forceinline__ unsigned pack4_fp8(float a, float b, float c, float d) {
  int w = __builtin_amdgcn_cvt_pk_fp8_f32(a, b, 0, false);
  w = __builtin_amdgcn_cvt_pk_fp8_f32(c, d, w, true);
  return (unsigned)w;
}

// ---------------- dtype detection ----------------
__global__ void detect_dtypes(const unsigned* __restrict__ xw, const unsigned* __restrict__ eiw,
                              int* __restrict__ flags) {
  __shared__ int s_bf16, s_i64nz;
  int t = threadIdx.x;
  if (t == 0) { s_bf16 = 0; s_i64nz = 0; }
  __syncthreads();
  unsigned w = xw[t * 97];
  unsigned lo = w & 0xFFFFu;
  unsigned e = (lo >> 7) & 0xFF;
  int looks_bf16 = (lo == 0u) || (e >= 0x6A && e <= 0x86);
  atomicAdd(&s_bf16, looks_bf16);
  int k = t * 1031;
  int nz = (eiw[2 * k + 1] != 0u) ? 1 : 0;
  atomicAdd(&s_i64nz, nz);
  __syncthreads();
  if (t == 0) {
    flags[0] = (s_bf16 >= 192) ? 1 : 0;
    flags[1] = (s_i64nz == 0) ? 1 : 0;
  }
}

// ---------------- merged float-side canonicalization ----------------
struct ParamDesc { const void* src[12]; int off[13]; };

// range 0: x (vec4 groups) -> h_f32 + h8 ; range 1: params -> f32 ; range 2: Wl|Wr -> fp8
__global__ void canon_all(const void* __restrict__ xsrc, ParamDesc pd,
                          const void* __restrict__ w1, const void* __restrict__ w2,
                          float* __restrict__ h_f32, u8* __restrict__ h8,
                          float* __restrict__ params, u8* __restrict__ w8,
                          int n_x4, int n_par, int n_w, const int* __restrict__ flags) {
  int i = blockIdx.x * blockDim.x + threadIdx.x;
  int isbf = flags[0];
  if (i < n_x4) {
    float v0, v1, v2, v3;
    if (isbf) {
      bf16x4 u = ((const bf16x4*)xsrc)[i];
      v0 = (float)u[0]; v1 = (float)u[1]; v2 = (float)u[2]; v3 = (float)u[3];
    } else {
      float4 u = ((const float4*)xsrc)[i];
      v0 = u.x; v1 = u.y; v2 = u.z; v3 = u.w;
    }
    ((float4*)h_f32)[i] = make_float4(v0, v1, v2, v3);
    ((unsigned*)h8)[i] = pack4_fp8(v0, v1, v2, v3);
    return;
  }
  i -= n_x4;
  if (i < n_par) {
    int s = 0;
#pragma unroll
    for (int k = 1; k < 12; k++) if (i >= pd.off[k]) s = k;
    int j = i - pd.off[s];
    const void* sp = pd.src[s];
    params[i] = isbf ? (float)((const __bf16*)sp)[j] : ((const float*)sp)[j];
    return;
  }
  i -= n_par;
  if (i < 2 * n_w) {
    const void* sp = (i < n_w) ? w1 : w2;
    int j = (i < n_w) ? i : i - n_w;
    float v = isbf ? (float)((const __bf16*)sp)[j] : ((const float*)sp)[j];
    w8[i] = f32_to_fp8(v);
  }
}

// merged: edge_index + batch int canonicalization + degree count (incl self-loops)
__global__ void canon_ints(const void* __restrict__ ei_src, const void* __restrict__ bat_src,
                           int* __restrict__ ei32, int* __restrict__ bat32,
                           int* __restrict__ deg, int E, int N, const int* __restrict__ flags) {
  int i = blockIdx.x * blockDim.x + threadIdx.x;
  int total = 2 * E + N;
  if (i >= total) return;
  int i64 = flags[1];
  if (i < 2 * E) {
    int v = i64 ? (int)((const long long*)ei_src)[i] : ((const int*)ei_src)[i];
    ei32[i] = v;
    if (i >= E) atomicAdd(&deg[v], 1);
  } else {
    int j = i - 2 * E;
    int v = i64 ? (int)((const long long*)bat_src)[j] : ((const int*)bat_src)[j];
    bat32[j] = v;
    atomicAdd(&deg[j], 1);   // self-loop
  }
}

// ---------------- CSR scan ----------------
__global__ __launch_bounds__(256) void block_sums(const int* __restrict__ deg,
                                                  int* __restrict__ bsum, int N) {
  __shared__ int sh[256];
  int i = blockIdx.x * 256 + threadIdx.x;
  int t = threadIdx.x;
  sh[t] = (i < N) ? deg[i] : 0;
  __syncthreads();
  for (int off = 128; off > 0; off >>= 1) {
    if (t < off) sh[t] += sh[t + off];
    __syncthreads();
  }
  if (t == 0) bsum[blockIdx.x] = sh[0];
}

__global__ __launch_bounds__(256) void scan_bsums(const int* __restrict__ bsum,
                                                  int* __restrict__ bpref, int nblocks,
                                                  int* __restrict__ offs, int N) {
  __shared__ int sh[256];
  int t = threadIdx.x;
  int carry = 0;
  for (int base = 0; base < nblocks; base += 256) {
    int idx = base + t;
    int v = (idx < nblocks) ? bsum[idx] : 0;
    sh[t] = v;
    __syncthreads();
    for (int off = 1; off < 256; off <<= 1) {
      int u = (t >= off) ? sh[t - off] : 0;
      __syncthreads();
      sh[t] += u;
      __syncthreads();
    }
    if (idx < nblocks) bpref[idx] = carry + sh[t] - v;
    carry += sh[255];
    __syncthreads();
  }
  if (t == 0) offs[N] = carry;
}

__global__ __launch_bounds__(256) void write_offs(const int* __restrict__ deg,
                                                  const int* __restrict__ bpref,
                                                  int* __restrict__ offs,
                                                  int* __restrict__ cursor, int N) {
  __shared__ int sh[256];
  int i = blockIdx.x * 256 + threadIdx.x;
  int t = threadIdx.x;
  int v = (i < N) ? deg[i] : 0;
  sh[t] = v;
  __syncthreads();
  for (int off = 1; off < 256; off <<= 1) {
    int u = (t >= off) ? sh[t - off] : 0;
    __syncthreads();
    sh[t] += u;
    __syncthreads();
  }
  if (i < N) {
    int ex = bpref[blockIdx.x] + sh[t] - v;
    offs[i] = ex;
    cursor[i] = ex;
  }
}

// csr_src stores BYTE offsets (src*1024)
__global__ void fill_csr(const int* __restrict__ ei, int E, int N,
                         int* __restrict__ cursor, int* __restrict__ csr_src) {
  int e = blockIdx.x * blockDim.x + threadIdx.x;
  if (e >= E + N) return;
  int s, d;
  if (e < E) { s = ei[e]; d = ei[E + e]; } else { s = e - E; d = e - E; }
  int pos = atomicAdd(&cursor[d], 1);
  csr_src[pos] = s * 1024;
}

// ---------------- GEMM (fp8 in, fp8 out), swapped operands => packed stores ----------------
__global__ __launch_bounds__(256) void gemm_xlr(
    const u8* __restrict__ A8, const u8* __restrict__ Wl8,
    const u8* __restrict__ Wr8, const float* __restrict__ bl,
    const float* __restrict__ br, u8* __restrict__ out8, int Nrows) {
  __shared__ u64 As[128][19];
  __shared__ u64 Ws[128][19];
  const int jb = blockIdx.y;
  const u8* Wbase = (jb < 4) ? (Wl8 + (size_t)jb * 16384) : (Wr8 + (size_t)(jb - 4) * 16384);
  const float* biasbase = (jb < 4) ? (bl + jb * 128) : (br + (jb - 4) * 128);
  const int row0 = blockIdx.x * 128;
  const int tid = threadIdx.x;
  const int lane = tid & 63, wave = tid >> 6;
  const int wm = wave >> 1, wn = wave & 1;

#pragma unroll
  for (int p = 0; p < 4; p++) {
    int r = (tid >> 3) + p * 32;
    int qc = (tid & 7) * 2;
    int gr = row0 + r;
    uint4 av = make_uint4(0, 0, 0, 0);
    if (gr < Nrows) av = *(const uint4*)(A8 + (size_t)gr * 128 + qc * 8);
    As[r][qc]     = ((u64)av.y << 32) | av.x;
    As[r][qc + 1] = ((u64)av.w << 32) | av.z;
    uint4 wv = *(const uint4*)(Wbase + (size_t)r * 128 + qc * 8);
    Ws[r][qc]     = ((u64)wv.y << 32) | wv.x;
    Ws[r][qc + 1] = ((u64)wv.w << 32) | wv.z;
  }
  __syncthreads();

  f32x4 acc[4][4];
#pragma unroll
  for (int mi = 0; mi < 4; mi++)
#pragma unroll
    for (int ni = 0; ni < 4; ni++) acc[mi][ni] = f32x4{0.f, 0.f, 0.f, 0.f};

#pragma unroll
  for (int ks = 0; ks < 4; ks++) {
    int qk = ks * 4 + (lane >> 4);
    long af[4], bf[4];
#pragma unroll
    for (int i = 0; i < 4; i++) {
      af[i] = (long)As[wm * 64 + i * 16 + (lane & 15)][qk];
      bf[i] = (long)Ws[wn * 64 + i * 16 + (lane & 15)][qk];
    }
#pragma unroll
    for (int mi = 0; mi < 4; mi++)
#pragma unroll
      for (int ni = 0; ni < 4; ni++)
        acc[mi][ni] = __builtin_amdgcn_mfma_f32_16x16x32_fp8_fp8(bf[ni], af[mi], acc[mi][ni], 0, 0, 0);
  }

#pragma unroll
  for (int mi = 0; mi < 4; mi++) {
    int gr = row0 + wm * 64 + mi * 16 + (lane & 15);
    if (gr >= Nrows) continue;
#pragma unroll
    for (int ni = 0; ni < 4; ni++) {
      int col_base = wn * 64 + ni * 16 + (lane >> 4) * 4;   // 4 consecutive cols
      float4 b4 = *(const float4*)(biasbase + col_base);
      unsigned pk = pack4_fp8(acc[mi][ni][0] + b4.x, acc[mi][ni][1] + b4.y,
                              acc[mi][ni][2] + b4.z, acc[mi][ni][3] + b4.w);
      *(unsigned*)(out8 + (size_t)gr * 1024 + jb * 128 + col_base) = pk;
    }
  }
}

// ---------------- fused GAT layer (fp8 gather, 2-edge form) ----------------
__global__ __launch_bounds__(256) void gat_fused(
    const u8* __restrict__ comb8, const float* __restrict__ att,
    const int* __restrict__ offs, const int* __restrict__ csr_src,
    const float* __restrict__ conv_bias, const float* __restrict__ gamma,
    const float* __restrict__ beta, float* __restrict__ h_f32,
    u8* __restrict__ h8, int N, int store_fp8) {
  int wid = blockIdx.x * 4 + (threadIdx.x >> 6);
  int lane = threadIdx.x & 63;
  if (wid >= N) return;
  int n = wid;
  f32x2 xr2[4], at2[4];
  uint2 wr = *(const uint2*)(comb8 + (size_t)n * 1024 + 512 + lane * 8);
  xr2[0] = __builtin_amdgcn_cvt_pk_f32_fp8(wr.x, false);
  xr2[1] = __builtin_amdgcn_cvt_pk_f32_fp8(wr.x, true);
  xr2[2] = __builtin_amdgcn_cvt_pk_f32_fp8(wr.y, false);
  xr2[3] = __builtin_amdgcn_cvt_pk_f32_fp8(wr.y, true);
  float4 a0 = *(const float4*)(att + lane * 8);
  float4 a1 = *(const float4*)(att + lane * 8 + 4);
  at2[0] = f32x2{a0.x, a0.y}; at2[1] = f32x2{a0.z, a0.w};
  at2[2] = f32x2{a1.x, a1.y}; at2[3] = f32x2{a1.z, a1.w};

  int off0 = offs[n], off1 = offs[n + 1];
  float l = 0.f;
  f32x2 acc2[4];
#pragma unroll
  for (int j = 0; j < 4; j++) acc2[j] = f32x2{0.f, 0.f};

  const u8* lane_base = comb8 + lane * 8;

  auto process = [&](uint2 w) {
    f32x2 x2[4];
    x2[0] = __builtin_amdgcn_cvt_pk_f32_fp8(w.x, false);
    x2[1] = __builtin_amdgcn_cvt_pk_f32_fp8(w.x, true);
    x2[2] = __builtin_amdgcn_cvt_pk_f32_fp8(w.y, false);
    x2[3] = __builtin_amdgcn_cvt_pk_f32_fp8(w.y, true);
    f32x2 t2 = f32x2{0.f, 0.f};
#pragma unroll
    for (int j = 0; j < 4; j++) {
      f32x2 z = x2[j] + xr2[j];
      f32x2 lz = __builtin_elementwise_max(z, 0.2f * z);   // leaky_relu, packed
      t2 = t2 + lz * at2[j];
    }
    float t = t2[0] + t2[1];
    t = row16_reduce(t);                 // 4 DPP VALU ops
    t = fminf(fmaxf(t, -60.f), 60.f);    // guard; softmax shift-invariant
    float p = __expf(t);
    l += p;
    f32x2 p2 = f32x2{p, p};
#pragma unroll
    for (int j = 0; j < 4; j++) acc2[j] = acc2[j] + p2 * x2[j];
  };

  int pos = off0;
  for (; pos + 2 <= off1; pos += 2) {
    int b0 = csr_src[pos], b1 = csr_src[pos + 1];  // premultiplied byte offsets
    uint2 wa = *(const uint2*)(lane_base + (size_t)(unsigned)b0);
    uint2 wb = *(const uint2*)(lane_base + (size_t)(unsigned)b1);
    process(wa);
    process(wb);
  }
  if (pos < off1) {
    int b0 = csr_src[pos];
    uint2 wa = *(const uint2*)(lane_base + (size_t)(unsigned)b0);
    process(wa);
  }

  float invl = 1.0f / fmaxf(l, 1e-30f);
  float acc[8];
#pragma unroll
  for (int j = 0; j < 4; j++) {
    acc[2 * j]     = acc2[j][0] * invl;
    acc[2 * j + 1] = acc2[j][1] * invl;
  }
#pragma unroll
  for (int j = 0; j < 8; j++) {
    acc[j] += __shfl_xor(acc[j], 16);
    acc[j] += __shfl_xor(acc[j], 32);
  }
  int c0 = (lane & 15) * 8;
  float v[8];
  float s = 0.f, s2 = 0.f;
#pragma unroll
  for (int j = 0; j < 8; j++) {
    v[j] = acc[j] * 0.25f + conv_bias[c0 + j];
    s += v[j]; s2 += v[j] * v[j];
  }
  s = row16_reduce(s);
  s2 = row16_reduce(s2);
  float mu = s * (1.f / 128.f);
  float var = fmaxf(s2 * (1.f / 128.f) - mu * mu, 0.f);
  float rs = rsqrtf(var + EPS);
  if (lane < 16) {
    float4 o0, o1;
    float hn[8];
#pragma unroll
    for (int j = 0; j < 8; j++) {
      float o = (v[j] - mu) * rs * gamma[c0 + j] + beta[c0 + j];
      o = o > 0.f ? o : 0.f;
      hn[j] = h_f32[(size_t)n * 128 + c0 + j] + o;
    }
    o0.x = hn[0]; o0.y = hn[1]; o0.z = hn[2]; o0.w = hn[3];
    o1.x = hn[4]; o1.y = hn[5]; o1.z = hn[6]; o1.w = hn[7];
    *(float4*)(h_f32 + (size_t)n * 128 + c0) = o0;
    *(float4*)(h_f32 + (size_t)n * 128 + c0 + 4) = o1;
    if (store_fp8) {
      uint2 pk;
      pk.x = pack4_fp8(hn[0], hn[1], hn[2], hn[3]);
      pk.y = pack4_fp8(hn[4], hn[5], hn[6], hn[7]);
      *(uint2*)(h8 + (size_t)n * 128 + c0) = pk;
    }
  }
}

// ---------------- global mean pool (separate, wide launch) ----------------
__global__ __launch_bounds__(128) void pool(const float* __restrict__ h_f32,
                                            const int* __restrict__ batch, int N,
                                            float* __restrict__ g_sum) {
  int g = blockIdx.x >> 4, slice = blockIdx.x & 15;
  int c = threadIdx.x;
  int r0 = lower_bound_i(batch, N, g);
  int r1 = lower_bound_i(batch, N, g + 1);
  int len = r1 - r0;
  if (len <= 0) return;
  int per = (len + 15) / 16;
  int s0 = r0 + slice * per;
  int s1 = min(s0 + per, r1);
  if (s0 >= s1) return;
  float acc = 0.f;
  for (int r = s0; r < s1; r++) acc += h_f32[(size_t)r * 128 + c];
  atomicAdd(&g_sum[g * 128 + c], acc);
}

// ---------------- MLP head + output layernorm ----------------
__global__ __launch_bounds__(256) void mlp_head(
    const float* __restrict__ g_sum, const int* __restrict__ batch, int N,
    const float* __restrict__ W1, const float* __restrict__ b1,
    const float* __restrict__ W2, const float* __restrict__ b2,
    const float* __restrict__ og, const float* __restrict__ ob,
    void* __restrict__ outv, const int* __restrict__ flags) {
  __shared__ float gld[128];
  __shared__ float hid[256];
  __shared__ float olds[128];
  __shared__ float red[2];
  int b = blockIdx.x, t = threadIdx.x;
  int r0 = lower_bound_i(batch, N, b);
  int r1 = lower_bound_i(batch, N, b + 1);
  int len = r1 - r0;
  float cntf = (float)(len < 1 ? 1 : len);
  if (t < 128) gld[t] = g_sum[b * 128 + t] / cntf;
  __syncthreads();
  float sacc = b1[t];
  for (int d = 0; d < 128; d++) sacc = fmaf(gld[d], W1[(size_t)t * 128 + d], sacc);
  hid[t] = 0.5f * sacc * (1.f + erff(sacc * 0.70710678118654752f));
  __syncthreads();
  if (t < 128) {
    float o = b2[t];
    for (int k = 0; k < 256; k++) o = fmaf(hid[k], W2[(size_t)t * 256 + k], o);
    olds[t] = o;
  }
  __syncthreads();
  if (t < 64) {
    float a = olds[t], bb = olds[t + 64];
    float s = a + bb, s2 = a * a + bb * bb;
    for (int off = 32; off; off >>= 1) { s += __shfl_down(s, off); s2 += __shfl_down(s2, off); }
    if (t == 0) { red[0] = s * (1.f / 128.f); red[1] = s2 * (1.f / 128.f); }
  }
  __syncthreads();
  if (t < 128) {
    float mu = red[0];
    float var = fmaxf(red[1] - mu * mu, 0.f);
    float rs = rsqrtf(var + EPS);
    float o = (olds[t] - mu) * rs * og[t] + ob[t];
    if (flags[0]) ((__bf16*)outv)[b * 128 + t] = (__bf16)o;
    else          ((float*)outv)[b * 128 + t] = o;
  }
}

extern "C" void kernel_launch(void* const* d_in, const int* in_sizes, int n_in,
                              void* d_out, int out_size, void* d_ws, size_t ws_size,
                              hipStream_t stream) {
  const int D = 128, B = 64;
  const int N = in_sizes[0] / D;
  const int E = in_sizes[1] / 2;
  const int EN = E + N;
  const int nsb = (N + 255) / 256;

  char* p = (char*)d_ws;
  auto alloc = [&](size_t bytes) {
    char* r = p; p += (bytes + 255) & ~(size_t)255; return (void*)r;
  };
  int* flags     = (int*)alloc(256);
  float* h_f32   = (float*)alloc((size_t)N * 128 * 4);
  u8* h8         = (u8*)alloc((size_t)N * 128);
  u8* comb8      = (u8*)alloc((size_t)N * 1024);
  int* deg       = (int*)alloc((size_t)N * 4);
  int* offs      = (int*)alloc((size_t)(N + 1) * 4);
  int* cursor    = (int*)alloc((size_t)N * 4);
  int* csr_src   = (int*)alloc((size_t)EN * 4);
  float* g_sum   = (float*)alloc((size_t)B * 128 * 4);
  int* ei32      = (int*)alloc((size_t)2 * E * 4);
  int* bat32     = (int*)alloc((size_t)N * 4);
  int* bsum      = (int*)alloc((size_t)nsb * 4);
  int* bpref     = (int*)alloc((size_t)nsb * 4);
  u8* w8         = (u8*)alloc((size_t)2 * 196608);
  float* params  = (float*)alloc((size_t)71936 * 4);

  float* bl_c  = params + 0;
  float* br_c  = params + 1536;
  float* att_c = params + 3072;
  float* cb_c  = params + 4608;
  float* g_c   = params + 4992;
  float* b_c   = params + 5376;
  float* W1_c  = params + 5760;
  float* b1_c  = params + 38528;
  float* W2_c  = params + 38784;
  float* b2_c  = params + 71552;
  float* og_c  = params + 71680;
  float* ob_c  = params + 71808;

  detect_dtypes<<<1, 256, 0, stream>>>((const unsigned*)d_in[0], (const unsigned*)d_in[1], flags);

  ParamDesc pd;
  const int srcidx[12] = {4, 6, 7, 8, 9, 10, 11, 12, 13, 14, 15, 16};
  const int sizes12[12] = {1536, 1536, 1536, 384, 384, 384, 32768, 256, 32768, 128, 128, 128};
  int cum = 0;
  for (int k = 0; k < 12; k++) { pd.src[k] = d_in[srcidx[k]]; pd.off[k] = cum; cum += sizes12[k]; }
  pd.off[12] = cum;

  const int n_x4 = N * 32;
  const int n_w = 196608;
  const int canon_total = n_x4 + cum + 2 * n_w;
  canon_all<<<(canon_total + 255) / 256, 256, 0, stream>>>(
      d_in[0], pd, d_in[3], d_in[5], h_f32, h8, params, w8, n_x4, cum, n_w, flags);

  hipMemsetAsync(deg, 0, (size_t)N * 4, stream);
  hipMemsetAsync(g_sum, 0, (size_t)B * 128 * 4, stream);

  canon_ints<<<(2 * E + N + 255) / 256, 256, 0, stream>>>(d_in[1], d_in[2], ei32, bat32, deg, E, N, flags);
  block_sums<<<nsb, 256, 0, stream>>>(deg, bsum, N);
  scan_bsums<<<1, 256, 0, stream>>>(bsum, bpref, nsb, offs, N);
  write_offs<<<nsb, 256, 0, stream>>>(deg, bpref, offs, cursor, N);
  fill_csr<<<(EN + 255) / 256, 256, 0, stream>>>(ei32, E, N, cursor, csr_src);

  for (int l = 0; l < 3; l++) {
    gemm_xlr<<<dim3((N + 127) / 128, 8), 256, 0, stream>>>(
        h8, w8 + (size_t)l * 65536, w8 + 196608 + (size_t)l * 65536,
        bl_c + l * 512, br_c + l * 512, comb8, N);
    gat_fused<<<(N + 3) / 4, 256, 0, stream>>>(comb8, att_c + l * 512, offs, csr_src,
        cb_c + l * 128, g_c + l * 128, b_c + l * 128, h_f32, h8, N, (l < 2) ? 1 : 0);
  }
  pool<<<B * 16, 128, 0, stream>>>(h_f32, bat32, N, g_sum);
  mlp_head<<<B, 256, 0, stream>>>(g_sum, bat32, N, W1_c, b1_c, W2_c, b2_c, og_c, ob_c, d_out, flags);
}